// Round 4
// baseline (3580.129 us; speedup 1.0000x reference)
//
#include <hip/hip_runtime.h>
#include <hip/hip_bf16.h>
#include <cstdint>
#include <cstddef>

// GRU: T=256, B=128, I=H=1024, 3H=3072. fp32 in/out.
// Phase 1: xg = x·W_ih^T + b_ih  (bf16 MFMA GEMM)
// Phase 2: persistent 128-block scan (32 col-groups x 4 batch-groups).
//   R3->R4: h broadcast via CACHED loads + one agent-acquire fence per step
//   (L2 shares the broadcast within an XCD); XCD-clustered bg mapping;
//   h-stores drained before flag, out/xg moved after; b128 LDS partials.

typedef __attribute__((ext_vector_type(4))) float f32x4;
typedef __attribute__((ext_vector_type(8))) short s16x8;
typedef __attribute__((ext_vector_type(4))) unsigned short u16x4;

static __device__ __forceinline__ unsigned short f2bf(float f) {
  union { float f; unsigned u; } v; v.f = f;
  unsigned u = v.u;
  u += 0x7FFFu + ((u >> 16) & 1u);   // RNE
  return (unsigned short)(u >> 16);
}
static __device__ __forceinline__ float bf2f(unsigned short h) {
  union { unsigned u; float f; } v; v.u = ((unsigned)h) << 16;
  return v.f;
}

// write-through 2B store to the device coherence point
static __device__ __forceinline__ void st_bypass(unsigned short* p, unsigned short v) {
  unsigned vv = v;
  asm volatile("global_store_short %0, %1, off sc0 sc1"
               :: "v"(p), "v"(vv) : "memory");
}
static __device__ __forceinline__ void st_flag(unsigned int* p, unsigned v) {
  asm volatile("global_store_dword %0, %1, off sc0 sc1"
               :: "v"(p), "v"(v) : "memory");
}
static __device__ __forceinline__ unsigned ld_flag(const unsigned int* p) {
  unsigned r;
  asm volatile("global_load_dword %0, %1, off sc0 sc1\n\ts_waitcnt vmcnt(0)"
               : "=v"(r) : "v"(p) : "memory");
  return r;
}

// ---------------- Phase 1: xg GEMM ----------------
template<bool XG_F32>
__global__ __launch_bounds__(256)
void xg_gemm(const float* __restrict__ X,     // [32768,1024]
             const float* __restrict__ W,     // [3072,1024]  (B^T layout)
             const float* __restrict__ bias,  // [3072]
             void* __restrict__ xg)           // [32768,3072] f32 or bf16
{
  __shared__ unsigned short Al[128][72];
  __shared__ unsigned short Bl[128][72];
  const int tid = threadIdx.x;
  const int lane = tid & 63;
  const int wv = tid >> 6;
  const int wm = (wv & 1) * 64;
  const int wn = (wv >> 1) * 64;
  const int m0 = blockIdx.y * 128;
  const int n0 = blockIdx.x * 128;
  const int r16 = lane & 15, r4 = lane >> 4;
  f32x4 acc[4][4] = {};

  for (int k0 = 0; k0 < 1024; k0 += 64) {
    __syncthreads();
    #pragma unroll
    for (int i = 0; i < 8; ++i) {
      int f4 = i * 256 + tid;
      int row = f4 >> 4;
      int c4 = f4 & 15;
      f32x4 a = *(const f32x4*)(X + (size_t)(m0 + row) * 1024 + k0 + c4 * 4);
      f32x4 b = *(const f32x4*)(W + (size_t)(n0 + row) * 1024 + k0 + c4 * 4);
      u16x4 ua = { f2bf(a.x), f2bf(a.y), f2bf(a.z), f2bf(a.w) };
      u16x4 ub = { f2bf(b.x), f2bf(b.y), f2bf(b.z), f2bf(b.w) };
      *(u16x4*)&Al[row][c4 * 4] = ua;
      *(u16x4*)&Bl[row][c4 * 4] = ub;
    }
    __syncthreads();
    #pragma unroll
    for (int kk = 0; kk < 64; kk += 32) {
      s16x8 af[4], bf[4];
      #pragma unroll
      for (int mi = 0; mi < 4; ++mi)
        af[mi] = *(const s16x8*)&Al[wm + mi * 16 + r16][kk + r4 * 8];
      #pragma unroll
      for (int ni = 0; ni < 4; ++ni)
        bf[ni] = *(const s16x8*)&Bl[wn + ni * 16 + r16][kk + r4 * 8];
      #pragma unroll
      for (int mi = 0; mi < 4; ++mi)
        #pragma unroll
        for (int ni = 0; ni < 4; ++ni)
          acc[mi][ni] = __builtin_amdgcn_mfma_f32_16x16x32_bf16(af[mi], bf[ni], acc[mi][ni], 0, 0, 0);
    }
  }
  #pragma unroll
  for (int ni = 0; ni < 4; ++ni) {
    float bv = bias[n0 + wn + ni * 16 + r16];
    #pragma unroll
    for (int mi = 0; mi < 4; ++mi) {
      #pragma unroll
      for (int r = 0; r < 4; ++r) {
        int m = m0 + wm + mi * 16 + r4 * 4 + r;
        int n = n0 + wn + ni * 16 + r16;
        float v = acc[mi][ni][r] + bv;
        if (XG_F32) ((float*)xg)[(size_t)m * 3072 + n] = v;
        else        ((unsigned short*)xg)[(size_t)m * 3072 + n] = f2bf(v);
      }
    }
  }
}

// ---------------- Phase 2: persistent GRU scan ----------------
// 128 blocks; id&7 -> XCD (empirical); bg=(id&7)>>1 so each batch-group's
// 32 blocks sit on one XCD pair -> h broadcast served by L2 after the
// per-step acquire fence. cg = (id>>3)*2 + (id&1).
template<bool XG_F32>
__global__ __launch_bounds__(512)
void gru_scan(const void* __restrict__ xg_,
              const float* __restrict__ Whh,   // [3072,1024]
              const float* __restrict__ bhh,   // [3072]
              float* __restrict__ out,         // [256,128,1024]
              unsigned short* __restrict__ hbc,// 2 parities x [128][1024] bf16
              unsigned int* __restrict__ bar)  // 4 x 32 flags
{
  __shared__ float part[4][3][2][2][16][20];   // [q][gate][ntile][mtile][gcol][brow+pad]
  const int tid = threadIdx.x;
  const int lane = tid & 63;
  const int wv = tid >> 6;        // K-eighth
  const int id = blockIdx.x;
  const int j8 = id & 7;
  const int bg = j8 >> 1;         // 0..3  (XCD pair {2bg,2bg+1})
  const int cg = ((id >> 3) << 1) | (j8 & 1);   // 0..31
  const int c0 = cg * 32;
  const int b0 = bg * 32;
  const int r16 = lane & 15, r4 = lane >> 4;

  // W_hh fragments in registers: bw[gate][ntile][kc]
  s16x8 bw[3][2][4];
  #pragma unroll
  for (int n = 0; n < 3; ++n) {
    #pragma unroll
    for (int nt = 0; nt < 2; ++nt) {
      const float* wrow = Whh + (size_t)(n * 1024 + c0 + nt * 16 + r16) * 1024;
      #pragma unroll
      for (int kc = 0; kc < 4; ++kc) {
        int k = wv * 128 + kc * 32 + r4 * 8;
        f32x4 v0 = *(const f32x4*)(wrow + k);
        f32x4 v1 = *(const f32x4*)(wrow + k + 4);
        s16x8 f;
        f[0] = (short)f2bf(v0.x); f[1] = (short)f2bf(v0.y);
        f[2] = (short)f2bf(v0.z); f[3] = (short)f2bf(v0.w);
        f[4] = (short)f2bf(v1.x); f[5] = (short)f2bf(v1.y);
        f[6] = (short)f2bf(v1.z); f[7] = (short)f2bf(v1.w);
        bw[n][nt][kc] = f;
      }
    }
  }

  const int p_c = tid & 31;       // h-col within group
  const int rb = tid >> 5;        // 0..15: owns batch rows rb and rb+16
  const int nt_g = p_c >> 4, c16 = p_c & 15;
  const float bR = bhh[c0 + p_c];
  const float bZ = bhh[1024 + c0 + p_c];
  const float bN = bhh[2048 + c0 + p_c];
  float hprev0 = 0.f, hprev1 = 0.f;
  const float* xgf = (const float*)xg_;
  const unsigned short* xgh = (const unsigned short*)xg_;
  unsigned int* flags = bar + bg * 32;
  const size_t arow0 = (size_t)(b0 + r16) * 1024;

  for (int t = 0; t < 256; ++t) {
    // acquire for this step's h parity: one L2/L1 invalidate per step
    __builtin_amdgcn_fence(__ATOMIC_ACQUIRE, "agent");

    const unsigned short* hH = hbc + (size_t)(t & 1) * 131072;

    // cached h loads (L2-shared within the XCD pair)
    s16x8 ah[2][4];
    #pragma unroll
    for (int kc = 0; kc < 4; ++kc) {
      int k = wv * 128 + kc * 32 + r4 * 8;
      ah[0][kc] = *(const s16x8*)(hH + arow0 + k);
      ah[1][kc] = *(const s16x8*)(hH + arow0 + 16384 + k);
    }

    // xg for this step (consumed in gate phase; latency hides under MFMA)
    float xr0, xz0, xn0, xr1, xz1, xn1;
    {
      size_t xi = ((size_t)(t * 128 + b0 + rb)) * 3072 + c0 + p_c;
      size_t xj = xi + (size_t)16 * 3072;
      if (XG_F32) {
        xr0 = xgf[xi]; xz0 = xgf[xi + 1024]; xn0 = xgf[xi + 2048];
        xr1 = xgf[xj]; xz1 = xgf[xj + 1024]; xn1 = xgf[xj + 2048];
      } else {
        xr0 = bf2f(xgh[xi]); xz0 = bf2f(xgh[xi + 1024]); xn0 = bf2f(xgh[xi + 2048]);
        xr1 = bf2f(xgh[xj]); xz1 = bf2f(xgh[xj + 1024]); xn1 = bf2f(xgh[xj + 2048]);
      }
    }

    f32x4 acc[3][2][2] = {};
    #pragma unroll
    for (int kc = 0; kc < 4; ++kc)
      #pragma unroll
      for (int n = 0; n < 3; ++n)
        #pragma unroll
        for (int nt = 0; nt < 2; ++nt) {
          acc[n][nt][0] = __builtin_amdgcn_mfma_f32_16x16x32_bf16(ah[0][kc], bw[n][nt][kc], acc[n][nt][0], 0, 0, 0);
          acc[n][nt][1] = __builtin_amdgcn_mfma_f32_16x16x32_bf16(ah[1][kc], bw[n][nt][kc], acc[n][nt][1], 0, 0, 0);
        }

    // two-round partial reduce, b128 writes ([gcol][brow+pad20] layout)
    if (wv < 4) {
      #pragma unroll
      for (int n = 0; n < 3; ++n)
        #pragma unroll
        for (int nt = 0; nt < 2; ++nt)
          #pragma unroll
          for (int m = 0; m < 2; ++m)
            *(f32x4*)&part[wv][n][nt][m][r16][r4 * 4] = acc[n][nt][m];
    }
    __syncthreads();
    if (wv >= 4) {
      #pragma unroll
      for (int n = 0; n < 3; ++n)
        #pragma unroll
        for (int nt = 0; nt < 2; ++nt)
          #pragma unroll
          for (int m = 0; m < 2; ++m) {
            f32x4 v = *(const f32x4*)&part[wv - 4][n][nt][m][r16][r4 * 4];
            *(f32x4*)&part[wv - 4][n][nt][m][r16][r4 * 4] = v + acc[n][nt][m];
          }
    }
    __syncthreads();

    // gate phase: thread owns (rb, p_c) and (rb+16, p_c)
    float sr0 = bR, sz0 = bZ, sn0 = bN;
    float sr1 = bR, sz1 = bZ, sn1 = bN;
    #pragma unroll
    for (int q = 0; q < 4; ++q) {
      sr0 += part[q][0][nt_g][0][c16][rb];
      sz0 += part[q][1][nt_g][0][c16][rb];
      sn0 += part[q][2][nt_g][0][c16][rb];
      sr1 += part[q][0][nt_g][1][c16][rb];
      sz1 += part[q][1][nt_g][1][c16][rb];
      sn1 += part[q][2][nt_g][1][c16][rb];
    }
    float rg0 = 1.f / (1.f + expf(-(xr0 + sr0)));
    float zg0 = 1.f / (1.f + expf(-(xz0 + sz0)));
    float ng0 = tanhf(xn0 + rg0 * sn0);
    float h0 = (1.f - zg0) * ng0 + zg0 * hprev0;
    float rg1 = 1.f / (1.f + expf(-(xr1 + sr1)));
    float zg1 = 1.f / (1.f + expf(-(xz1 + sz1)));
    float ng1 = tanhf(xn1 + rg1 * sn1);
    float h1 = (1.f - zg1) * ng1 + zg1 * hprev1;
    hprev0 = h0; hprev1 = h1;

    // h broadcast: write-through stores, drained BEFORE the flag
    unsigned short* wH = hbc + (size_t)((t + 1) & 1) * 131072;
    size_t widx = (size_t)(b0 + rb) * 1024 + c0 + p_c;
    st_bypass(wH + widx, f2bf(h0));
    st_bypass(wH + widx + 16384, f2bf(h1));
    asm volatile("s_waitcnt vmcnt(0)" ::: "memory");
    __syncthreads();                    // all waves' h visible at coherence point

    if (tid == 0) st_flag(flags + cg, (unsigned)(t + 1));

    // off-critical-path: out stores (HBM) fly during the poll
    size_t oidx = (size_t)t * 131072 + (size_t)(b0 + rb) * 1024 + c0 + p_c;
    out[oidx] = h0;
    out[oidx + 16384] = h1;

    if (wv == 0) {
      unsigned tgt = (unsigned)(t + 1);
      for (;;) {
        unsigned v = ld_flag(flags + (lane & 31));
        if (!__ballot(v < tgt)) break;
        __builtin_amdgcn_s_sleep(1);
      }
    }
    __syncthreads();
  }
}

extern "C" void kernel_launch(void* const* d_in, const int* in_sizes, int n_in,
                              void* d_out, int out_size, void* d_ws, size_t ws_size,
                              hipStream_t stream) {
  const float* x   = (const float*)d_in[0];
  const float* wih = (const float*)d_in[1];
  const float* whh = (const float*)d_in[2];
  const float* bih = (const float*)d_in[3];
  const float* bhh = (const float*)d_in[4];
  float* out = (float*)d_out;

  const size_t xg_f32_bytes = (size_t)32768 * 3072 * 4;   // 384 MiB
  const size_t tail = 2 * 262144 + 512;                   // h ping-pong + flags
  const bool use_f32 = (ws_size >= xg_f32_bytes + tail);
  const size_t xg_bytes = use_f32 ? xg_f32_bytes : xg_f32_bytes / 2;

  char* ws = (char*)d_ws;
  void* xg = ws;
  unsigned short* hbc = (unsigned short*)(ws + xg_bytes);
  unsigned int* bar = (unsigned int*)(ws + xg_bytes + 2 * 262144);

  hipMemsetAsync(hbc, 0, tail, stream);
  if (use_f32) {
    xg_gemm<true><<<dim3(24, 256), 256, 0, stream>>>(x, wih, bih, xg);
    gru_scan<true><<<128, 512, 0, stream>>>(xg, whh, bhh, out, hbc, bar);
  } else {
    xg_gemm<false><<<dim3(24, 256), 256, 0, stream>>>(x, wih, bih, xg);
    gru_scan<false><<<128, 512, 0, stream>>>(xg, whh, bhh, out, hbc, bar);
  }
}

// Round 5
// 1506.708 us; speedup vs baseline: 2.3761x; 2.3761x over previous
//
#include <hip/hip_runtime.h>
#include <hip/hip_bf16.h>
#include <cstdint>
#include <cstddef>

// GRU: T=256, B=128, I=H=1024, 3H=3072. fp32 in/out.
// Phase 1: xg = x·W_ih^T + b_ih  (bf16 MFMA GEMM, bf16 output)
// Phase 2: persistent 256-block scan; 8 batch-groups(16 rows) x 32 col-groups(32 cols).
//   bg = blockIdx&7 -> clusters each bg on one XCD (empirical id%8->XCD).
//   Runtime XCC_ID detection: if co-resident, h exchange via sc0/L2 (XCD-local);
//   else sc0sc1/MALL fallback (always correct). Flags always MALL + memset.

typedef __attribute__((ext_vector_type(4))) float f32x4;
typedef __attribute__((ext_vector_type(8))) short s16x8;
typedef __attribute__((ext_vector_type(4))) unsigned short u16x4;

static __device__ __forceinline__ unsigned short f2bf(float f) {
  union { float f; unsigned u; } v; v.f = f;
  unsigned u = v.u;
  u += 0x7FFFu + ((u >> 16) & 1u);   // RNE
  return (unsigned short)(u >> 16);
}
static __device__ __forceinline__ float bf2f(unsigned short h) {
  union { unsigned u; float f; } v; v.u = ((unsigned)h) << 16;
  return v.f;
}

// L2-scope (XCD-local) ops: bypass L1 only
static __device__ __forceinline__ s16x8 ld16_l2(const unsigned short* p) {
  s16x8 r;
  asm volatile("global_load_dwordx4 %0, %1, off sc0" : "=v"(r) : "v"(p) : "memory");
  return r;
}
static __device__ __forceinline__ void st2_l2(unsigned short* p, unsigned short v) {
  unsigned vv = v;
  asm volatile("global_store_short %0, %1, off sc0" :: "v"(p), "v"(vv) : "memory");
}
// device-scope (MALL) ops
static __device__ __forceinline__ s16x8 ld16_mall(const unsigned short* p) {
  s16x8 r;
  asm volatile("global_load_dwordx4 %0, %1, off sc0 sc1" : "=v"(r) : "v"(p) : "memory");
  return r;
}
static __device__ __forceinline__ void st2_mall(unsigned short* p, unsigned short v) {
  unsigned vv = v;
  asm volatile("global_store_short %0, %1, off sc0 sc1" :: "v"(p), "v"(vv) : "memory");
}
static __device__ __forceinline__ void st_flag(unsigned int* p, unsigned v) {
  asm volatile("global_store_dword %0, %1, off sc0 sc1" :: "v"(p), "v"(v) : "memory");
}
static __device__ __forceinline__ unsigned ld_flag(const unsigned int* p) {
  unsigned r;
  asm volatile("global_load_dword %0, %1, off sc0 sc1\n\ts_waitcnt vmcnt(0)"
               : "=v"(r) : "v"(p) : "memory");
  return r;
}

// ---------------- Phase 1: xg GEMM (bf16 out) ----------------
__global__ __launch_bounds__(256)
void xg_gemm(const float* __restrict__ X,     // [32768,1024]
             const float* __restrict__ W,     // [3072,1024]
             const float* __restrict__ bias,  // [3072]
             unsigned short* __restrict__ xg) // [32768,3072] bf16
{
  __shared__ unsigned short Al[128][72];
  __shared__ unsigned short Bl[128][72];
  const int tid = threadIdx.x;
  const int lane = tid & 63;
  const int wv = tid >> 6;
  const int wm = (wv & 1) * 64;
  const int wn = (wv >> 1) * 64;
  const int m0 = blockIdx.y * 128;
  const int n0 = blockIdx.x * 128;
  const int r16 = lane & 15, r4 = lane >> 4;
  f32x4 acc[4][4] = {};

  for (int k0 = 0; k0 < 1024; k0 += 64) {
    __syncthreads();
    #pragma unroll
    for (int i = 0; i < 8; ++i) {
      int f4 = i * 256 + tid;
      int row = f4 >> 4;
      int c4 = f4 & 15;
      f32x4 a = *(const f32x4*)(X + (size_t)(m0 + row) * 1024 + k0 + c4 * 4);
      f32x4 b = *(const f32x4*)(W + (size_t)(n0 + row) * 1024 + k0 + c4 * 4);
      u16x4 ua = { f2bf(a.x), f2bf(a.y), f2bf(a.z), f2bf(a.w) };
      u16x4 ub = { f2bf(b.x), f2bf(b.y), f2bf(b.z), f2bf(b.w) };
      *(u16x4*)&Al[row][c4 * 4] = ua;
      *(u16x4*)&Bl[row][c4 * 4] = ub;
    }
    __syncthreads();
    #pragma unroll
    for (int kk = 0; kk < 64; kk += 32) {
      s16x8 af[4], bf[4];
      #pragma unroll
      for (int mi = 0; mi < 4; ++mi)
        af[mi] = *(const s16x8*)&Al[wm + mi * 16 + r16][kk + r4 * 8];
      #pragma unroll
      for (int ni = 0; ni < 4; ++ni)
        bf[ni] = *(const s16x8*)&Bl[wn + ni * 16 + r16][kk + r4 * 8];
      #pragma unroll
      for (int mi = 0; mi < 4; ++mi)
        #pragma unroll
        for (int ni = 0; ni < 4; ++ni)
          acc[mi][ni] = __builtin_amdgcn_mfma_f32_16x16x32_bf16(af[mi], bf[ni], acc[mi][ni], 0, 0, 0);
    }
  }
  #pragma unroll
  for (int ni = 0; ni < 4; ++ni) {
    float bv = bias[n0 + wn + ni * 16 + r16];
    #pragma unroll
    for (int mi = 0; mi < 4; ++mi) {
      #pragma unroll
      for (int r = 0; r < 4; ++r) {
        int m = m0 + wm + mi * 16 + r4 * 4 + r;
        int n = n0 + wn + ni * 16 + r16;
        xg[(size_t)m * 3072 + n] = f2bf(acc[mi][ni][r] + bv);
      }
    }
  }
}

// ---------------- Phase 2: persistent GRU scan ----------------
// 256 blocks: bg = id&7 (16 batch rows), cg = id>>3 (32 h-cols).
// 8 waves: ks = wv>>1 (K-quarter), nt = wv&1 (16-col half).
__global__ __launch_bounds__(512, 2)
void gru_scan(const unsigned short* __restrict__ xg,  // [32768,3072] bf16
              const float* __restrict__ Whh,          // [3072,1024]
              const float* __restrict__ bhh,          // [3072]
              float* __restrict__ out,                // [256,128,1024]
              unsigned short* __restrict__ hbc,       // 2 x [128][1024] bf16
              unsigned int* __restrict__ bar)         // flags/det regions
{
  __shared__ char hraw[32768];           // swizzled [16][1024] bf16 h tile
  __shared__ float part[6][3][64][4];    // K-partials, lane-dense (conflict-free)
  __shared__ int fastsh;

  const int tid = threadIdx.x;
  const int lane = tid & 63;
  const int wv = tid >> 6;
  const int id = blockIdx.x;
  const int bg = id & 7;
  const int cg = id >> 3;
  const int c0 = cg * 32;
  const int b0 = bg * 16;
  const int r16 = lane & 15, r4 = lane >> 4;
  const int ks = wv >> 1, nt = wv & 1;

  unsigned int* sflags = bar + bg * 256;          // 32 step-flags, 1KB/group
  unsigned int* dflags = bar + 2048 + bg * 256;   // 32 det-flags

  // ---- XCD co-residency detection (HW_REG_XCC_ID = hwreg 20, size 32) ----
  unsigned myxcc = (__builtin_amdgcn_s_getreg(63508) & 0xFu) | 0x100u;
  if (tid == 0) st_flag(dflags + cg, myxcc);
  if (wv == 0) {
    unsigned v;
    for (;;) {
      v = ld_flag(dflags + (lane & 31));
      if (__ballot(v < 0x100u) == 0) break;
      __builtin_amdgcn_s_sleep(1);
    }
    int bad = (v != myxcc);
    if (tid == 0) fastsh = (__ballot(bad) == 0) ? 1 : 0;
  }
  __syncthreads();
  const bool fast = (fastsh != 0);

  // ---- W_hh fragments in registers: bw[gate][kc] (24 x s16x8 = 96 VGPR) ----
  s16x8 bw[3][8];
  #pragma unroll
  for (int n = 0; n < 3; ++n) {
    const float* wrow = Whh + (size_t)(n * 1024 + c0 + nt * 16 + r16) * 1024;
    #pragma unroll
    for (int kc = 0; kc < 8; ++kc) {
      int k = ks * 256 + kc * 32 + r4 * 8;
      f32x4 v0 = *(const f32x4*)(wrow + k);
      f32x4 v1 = *(const f32x4*)(wrow + k + 4);
      s16x8 f;
      f[0] = (short)f2bf(v0.x); f[1] = (short)f2bf(v0.y);
      f[2] = (short)f2bf(v0.z); f[3] = (short)f2bf(v0.w);
      f[4] = (short)f2bf(v1.x); f[5] = (short)f2bf(v1.y);
      f[6] = (short)f2bf(v1.z); f[7] = (short)f2bf(v1.w);
      bw[n][kc] = f;
    }
  }

  // gate-phase constants (meaningful for wv<2 only)
  const int gcol = c0 + nt * 16 + r16;
  const float bR = bhh[gcol];
  const float bZ = bhh[1024 + gcol];
  const float bN = bhh[2048 + gcol];
  float hprev[4] = {0.f, 0.f, 0.f, 0.f};
  float xqr[4], xqz[4], xqn[4];
  if (wv < 2) {
    #pragma unroll
    for (int r = 0; r < 4; ++r) {
      size_t xi = ((size_t)(b0 + r4 * 4 + r)) * 3072 + gcol;
      xqr[r] = bf2f(xg[xi]); xqz[r] = bf2f(xg[xi + 1024]); xqn[r] = bf2f(xg[xi + 2048]);
    }
  }

  // zero h tile (h0 = 0); then no staging needed at t=0
  #pragma unroll
  for (int i = 0; i < 4; ++i)
    *(f32x4*)(hraw + tid * 64 + i * 16) = (f32x4){0.f, 0.f, 0.f, 0.f};
  __syncthreads();

  // A-frag read addressing (swizzled)
  const int arow = lane & 15;
  const int aswz = (arow & 7) << 4;
  const int abase = arow * 2048;
  const int g16 = (lane >> 4) * 16;

  // staging addressing: thread covers rows {i*4+ks}, colbyte = nt*1024 + lane*16
  const int scb = nt * 1024 + lane * 16;
  int s_goff[4], s_loff[4];
  #pragma unroll
  for (int i = 0; i < 4; ++i) {
    int row = i * 4 + ks;
    s_goff[i] = (b0 + row) * 1024 + (scb >> 1);            // elem offset
    s_loff[i] = row * 2048 + (scb ^ ((row & 7) << 4));     // lds byte offset
  }

  for (int t = 0; t < 256; ++t) {
    // ---- MFMA over h[t] (LDS tile) ----
    f32x4 a0 = {0.f,0.f,0.f,0.f}, a1 = a0, a2 = a0;
    #pragma unroll
    for (int kc = 0; kc < 8; ++kc) {
      s16x8 a = *(const s16x8*)(hraw + abase + ((ks * 512 + kc * 64 + g16) ^ aswz));
      a0 = __builtin_amdgcn_mfma_f32_16x16x32_bf16(a, bw[0][kc], a0, 0, 0, 0);
      a1 = __builtin_amdgcn_mfma_f32_16x16x32_bf16(a, bw[1][kc], a1, 0, 0, 0);
      a2 = __builtin_amdgcn_mfma_f32_16x16x32_bf16(a, bw[2][kc], a2, 0, 0, 0);
    }
    if (ks > 0) {
      int pi = (ks - 1) * 2 + nt;
      *(f32x4*)&part[pi][0][lane][0] = a0;
      *(f32x4*)&part[pi][1][lane][0] = a1;
      *(f32x4*)&part[pi][2][lane][0] = a2;
    }
    __syncthreads();

    if (ks == 0) {
      #pragma unroll
      for (int kx = 0; kx < 3; ++kx) {
        a0 += *(const f32x4*)&part[kx * 2 + nt][0][lane][0];
        a1 += *(const f32x4*)&part[kx * 2 + nt][1][lane][0];
        a2 += *(const f32x4*)&part[kx * 2 + nt][2][lane][0];
      }
      unsigned short* wH = hbc + (size_t)((t + 1) & 1) * 131072;
      float hnew[4];
      #pragma unroll
      for (int r = 0; r < 4; ++r) {
        float rg = 1.f / (1.f + expf(-(xqr[r] + a0[r] + bR)));
        float zg = 1.f / (1.f + expf(-(xqz[r] + a1[r] + bZ)));
        float ng = tanhf(xqn[r] + rg * (a2[r] + bN));
        float h = (1.f - zg) * ng + zg * hprev[r];
        hprev[r] = h; hnew[r] = h;
        out[(size_t)t * 131072 + (size_t)(b0 + r4 * 4 + r) * 1024 + gcol] = h;
      }
      if (fast) {
        #pragma unroll
        for (int r = 0; r < 4; ++r)
          st2_l2(wH + (size_t)(b0 + r4 * 4 + r) * 1024 + gcol, f2bf(hnew[r]));
      } else {
        #pragma unroll
        for (int r = 0; r < 4; ++r)
          st2_mall(wH + (size_t)(b0 + r4 * 4 + r) * 1024 + gcol, f2bf(hnew[r]));
      }
      asm volatile("s_waitcnt vmcnt(0)" ::: "memory");
    }
    __syncthreads();

    if (tid == 0) st_flag(sflags + cg, (unsigned)(t + 1));

    if (t < 255) {
      // xg prefetch for t+1 overlaps the poll
      if (wv < 2) {
        #pragma unroll
        for (int r = 0; r < 4; ++r) {
          size_t xi = ((size_t)((t + 1) * 128 + b0 + r4 * 4 + r)) * 3072 + gcol;
          xqr[r] = bf2f(xg[xi]); xqz[r] = bf2f(xg[xi + 1024]); xqn[r] = bf2f(xg[xi + 2048]);
        }
      }
      if (wv == 7) {
        unsigned tgt = (unsigned)(t + 1);
        for (;;) {
          unsigned v = ld_flag(sflags + (lane & 31));
          if (__ballot(v < tgt) == 0) break;
          __builtin_amdgcn_s_sleep(1);
        }
      }
      __syncthreads();

      // stage h[t+1] into LDS (swizzled)
      const unsigned short* hs = hbc + (size_t)((t + 1) & 1) * 131072;
      s16x8 v0, v1, v2, v3;
      if (fast) {
        v0 = ld16_l2(hs + s_goff[0]); v1 = ld16_l2(hs + s_goff[1]);
        v2 = ld16_l2(hs + s_goff[2]); v3 = ld16_l2(hs + s_goff[3]);
      } else {
        v0 = ld16_mall(hs + s_goff[0]); v1 = ld16_mall(hs + s_goff[1]);
        v2 = ld16_mall(hs + s_goff[2]); v3 = ld16_mall(hs + s_goff[3]);
      }
      asm volatile("s_waitcnt vmcnt(0)" ::: "memory");
      *(s16x8*)(hraw + s_loff[0]) = v0;
      *(s16x8*)(hraw + s_loff[1]) = v1;
      *(s16x8*)(hraw + s_loff[2]) = v2;
      *(s16x8*)(hraw + s_loff[3]) = v3;
      __syncthreads();
    }
  }
}

extern "C" void kernel_launch(void* const* d_in, const int* in_sizes, int n_in,
                              void* d_out, int out_size, void* d_ws, size_t ws_size,
                              hipStream_t stream) {
  const float* x   = (const float*)d_in[0];
  const float* wih = (const float*)d_in[1];
  const float* whh = (const float*)d_in[2];
  const float* bih = (const float*)d_in[3];
  const float* bhh = (const float*)d_in[4];
  float* out = (float*)d_out;

  const size_t xg_bytes = (size_t)32768 * 3072 * 2;   // 192 MiB bf16
  char* ws = (char*)d_ws;
  unsigned short* xg = (unsigned short*)ws;
  unsigned short* hbc = (unsigned short*)(ws + xg_bytes);
  unsigned int* bar = (unsigned int*)(ws + xg_bytes + 2 * 262144);

  hipMemsetAsync(bar, 0, 16384, stream);   // step-flags + det-flags
  xg_gemm<<<dim3(24, 256), 256, 0, stream>>>(x, wih, bih, xg);
  gru_scan<<<256, 512, 0, stream>>>(xg, whh, bhh, out, hbc, bar);
}